// Round 2
// baseline (329.704 us; speedup 1.0000x reference)
//
#include <hip/hip_runtime.h>
#include <stdint.h>

#define NB 4096   // query rows
#define NM 8192   // memory rows
#define ND 1024   // feature dim

typedef __attribute__((ext_vector_type(8))) short bf16x8;
typedef __attribute__((ext_vector_type(4))) float f32x4;
typedef __attribute__((ext_vector_type(8))) unsigned short u16x8;

static __device__ __forceinline__ unsigned short f2bf(float f) {
  union { float f; uint32_t u; } v; v.f = f;
  uint32_t u = v.u;
  u += 0x7fffu + ((u >> 16) & 1u);   // RNE
  return (unsigned short)(u >> 16);
}

static __device__ __forceinline__ void gload_lds16(const void* g, void* l) {
  __builtin_amdgcn_global_load_lds(
      (__attribute__((address_space(1))) void*)g,
      (__attribute__((address_space(3))) void*)l, 16, 0, 0);
}

// ---- L2-normalize rows of x [rows x 1024] fp32 -> bf16 out -----------------
__global__ void nrm_kernel(const float* __restrict__ x, unsigned short* __restrict__ out) {
  const int row = blockIdx.x, t = threadIdx.x;   // 256 threads, 4 floats each
  const float4 v = ((const float4*)(x + (size_t)row * ND))[t];
  float ss = v.x * v.x + v.y * v.y + v.z * v.z + v.w * v.w;
  #pragma unroll
  for (int o = 32; o > 0; o >>= 1) ss += __shfl_xor(ss, o);
  __shared__ float red[4];
  if ((t & 63) == 0) red[t >> 6] = ss;
  __syncthreads();
  ss = (red[0] + red[1]) + (red[2] + red[3]);
  const float sc = 1.0f / fmaxf(sqrtf(ss), 1e-12f);
  ushort4 o4;
  o4.x = f2bf(v.x * sc); o4.y = f2bf(v.y * sc);
  o4.z = f2bf(v.z * sc); o4.w = f2bf(v.w * sc);
  ((ushort4*)(out + (size_t)row * ND))[t] = o4;
}

// ---- transpose memn [8192x1024] bf16 -> memt [1024x8192] bf16 --------------
__global__ void tr_kernel(const unsigned short* __restrict__ memn, unsigned short* __restrict__ memt) {
  __shared__ unsigned short Ts[64][66];
  const int t = threadIdx.x;
  const int d0 = blockIdx.x * 64, m0 = blockIdx.y * 64;
  #pragma unroll
  for (int r = 0; r < 2; ++r) {
    const int lrow = r * 32 + (t >> 3);
    const int lcol = (t & 7) * 8;
    u16x8 v = *(const u16x8*)(memn + (size_t)(m0 + lrow) * ND + d0 + lcol);
    #pragma unroll
    for (int j = 0; j < 8; ++j) Ts[lcol + j][lrow] = v[j];
  }
  __syncthreads();
  #pragma unroll
  for (int r = 0; r < 2; ++r) {
    const int orow = r * 32 + (t >> 3);
    const int ocol = (t & 7) * 8;
    u16x8 o;
    #pragma unroll
    for (int j = 0; j < 8; ++j) o[j] = Ts[orow][ocol + j];
    *(u16x8*)(memt + (size_t)(d0 + orow) * NM + m0 + ocol) = o;
  }
}

// ---- row softmax in-place on sim [4096x8192] fp32; optional bf16 copy ------
__global__ void softmax_kernel(float* __restrict__ sim, unsigned short* __restrict__ attnb, int wb) {
  const int row = blockIdx.x, t = threadIdx.x;
  float* prow = sim + (size_t)row * NM;
  float4 v[8];
  #pragma unroll
  for (int i = 0; i < 8; ++i) v[i] = ((const float4*)prow)[i * 256 + t];
  float mx = -3.4e38f;
  #pragma unroll
  for (int i = 0; i < 8; ++i)
    mx = fmaxf(mx, fmaxf(fmaxf(v[i].x, v[i].y), fmaxf(v[i].z, v[i].w)));
  #pragma unroll
  for (int o = 32; o > 0; o >>= 1) mx = fmaxf(mx, __shfl_xor(mx, o));
  __shared__ float red[8];
  if ((t & 63) == 0) red[t >> 6] = mx;
  __syncthreads();
  mx = fmaxf(fmaxf(red[0], red[1]), fmaxf(red[2], red[3]));
  float s = 0.f;
  #pragma unroll
  for (int i = 0; i < 8; ++i) {
    v[i].x = __expf(v[i].x - mx); v[i].y = __expf(v[i].y - mx);
    v[i].z = __expf(v[i].z - mx); v[i].w = __expf(v[i].w - mx);
    s += (v[i].x + v[i].y) + (v[i].z + v[i].w);
  }
  #pragma unroll
  for (int o = 32; o > 0; o >>= 1) s += __shfl_xor(s, o);
  if ((t & 63) == 0) red[4 + (t >> 6)] = s;
  __syncthreads();
  s = (red[4] + red[5]) + (red[6] + red[7]);
  const float inv = 1.0f / s;
  #pragma unroll
  for (int i = 0; i < 8; ++i) {
    v[i].x *= inv; v[i].y *= inv; v[i].z *= inv; v[i].w *= inv;
    ((float4*)prow)[i * 256 + t] = v[i];
    if (wb) {
      ushort4 b;
      b.x = f2bf(v[i].x); b.y = f2bf(v[i].y); b.z = f2bf(v[i].z); b.w = f2bf(v[i].w);
      *(ushort4*)(attnb + (size_t)row * NM + (size_t)(i * 256 + t) * 4) = b;
    }
  }
}

// ---- GEMM: C[M,N] = A[M,K] * Bt[N,K]^T, bf16 MFMA, fp32 out ---------------
// 128x128 tile, BK=64, 256 threads (4 waves in 2x2), 16x16x32 bf16 MFMA.
// SWZ: 1-D grid with XCD-chunked bijective swizzle (nwg % 8 == 0 required).
template<bool A_BF16, bool SWZ>
__global__ __launch_bounds__(256) void gemm_kernel(
    const void* __restrict__ Ap, const unsigned short* __restrict__ Bt,
    float* __restrict__ C, int Kdim, int Ndim, int mt)
{
  __shared__ __align__(16) unsigned short As[128 * 64];
  __shared__ __align__(16) unsigned short Bs[128 * 64];
  const int t = threadIdx.x;
  const int wv = t >> 6, l = t & 63;
  const int wr = wv >> 1, wc = wv & 1;
  int brow, bcol;
  if constexpr (SWZ) {
    const int nwg = gridDim.x, cpx = nwg >> 3;
    const int id = (blockIdx.x & 7) * cpx + (blockIdx.x >> 3);
    brow = id % mt; bcol = id / mt;
  } else {
    brow = blockIdx.x; bcol = blockIdx.y;
  }
  const int srow = t >> 3;            // 0..31 row within a 32-row stage group
  const int scol = (t & 7) * 8;       // element col offset within 64-wide tile
  const int lr15 = l & 15, lhi = l >> 4;

  f32x4 acc[4][4] = {};

  for (int kt = 0; kt < Kdim; kt += 64) {
    if constexpr (A_BF16) {
      const unsigned short* A = (const unsigned short*)Ap;
      #pragma unroll
      for (int r = 0; r < 4; ++r)
        gload_lds16(A + (size_t)(brow * 128 + r * 32 + srow) * Kdim + kt + scol,
                    (char*)As + r * 4096 + wv * 1024);
    } else {
      const float* A = (const float*)Ap;    // fp32 attn -> cvt to bf16 in regs
      #pragma unroll
      for (int r = 0; r < 8; ++r) {
        const int idx4 = r * 256 + t;
        const int row = idx4 >> 4, c4 = (idx4 & 15) * 4;
        float4 fv = *(const float4*)(A + (size_t)(brow * 128 + row) * Kdim + kt + c4);
        ushort4 b;
        b.x = f2bf(fv.x); b.y = f2bf(fv.y); b.z = f2bf(fv.z); b.w = f2bf(fv.w);
        *(ushort4*)(As + row * 64 + c4) = b;
      }
    }
    #pragma unroll
    for (int r = 0; r < 4; ++r)
      gload_lds16(Bt + (size_t)(bcol * 128 + r * 32 + srow) * Kdim + kt + scol,
                  (char*)Bs + r * 4096 + wv * 1024);
    __syncthreads();
    #pragma unroll
    for (int kk = 0; kk < 2; ++kk) {
      bf16x8 a[4], b[4];
      #pragma unroll
      for (int m = 0; m < 4; ++m)
        a[m] = *(const bf16x8*)(As + (wr * 64 + m * 16 + lr15) * 64 + kk * 32 + lhi * 8);
      #pragma unroll
      for (int n = 0; n < 4; ++n)
        b[n] = *(const bf16x8*)(Bs + (wc * 64 + n * 16 + lr15) * 64 + kk * 32 + lhi * 8);
      #pragma unroll
      for (int m = 0; m < 4; ++m)
        #pragma unroll
        for (int n = 0; n < 4; ++n)
          acc[m][n] = __builtin_amdgcn_mfma_f32_16x16x32_bf16(a[m], b[n], acc[m][n], 0, 0, 0);
    }
    __syncthreads();
  }
  // C/D layout: col = lane&15, row = (lane>>4)*4 + reg  [learn_hip m89/m91]
  const int crow0 = brow * 128 + wr * 64 + lhi * 4;
  const int ccol0 = bcol * 128 + wc * 64 + lr15;
  #pragma unroll
  for (int m = 0; m < 4; ++m)
    #pragma unroll
    for (int n = 0; n < 4; ++n)
      #pragma unroll
      for (int j = 0; j < 4; ++j)
        C[(size_t)(crow0 + m * 16 + j) * Ndim + ccol0 + n * 16] = acc[m][n][j];
}

// ---- split-K GEMM2: part[k][4096x1024] = attnb[:, kr] * memt[:, kr]^T ------
// grid = 32(M) x 8(N) x S, 1-D with XCD swizzle; k-slice contiguous per chunk.
__global__ __launch_bounds__(256) void gemm_splitk_kernel(
    const unsigned short* __restrict__ A,   // attnb [4096 x 8192] bf16
    const unsigned short* __restrict__ Bt,  // memt  [1024 x 8192] bf16
    float* __restrict__ part, int kchunk)
{
  __shared__ __align__(16) unsigned short As[128 * 64];
  __shared__ __align__(16) unsigned short Bs[128 * 64];
  const int t = threadIdx.x;
  const int wv = t >> 6, l = t & 63;
  const int wr = wv >> 1, wc = wv & 1;
  const int nwg = gridDim.x, cpx = nwg >> 3;
  const int id = (blockIdx.x & 7) * cpx + (blockIdx.x >> 3);
  const int ksp = id >> 8;             // 256 = 32*8 tiles per k-slice
  const int rem = id & 255;
  const int brow = rem >> 3, bcol = rem & 7;
  const int k0 = ksp * kchunk;
  const int srow = t >> 3, scol = (t & 7) * 8;
  const int lr15 = l & 15, lhi = l >> 4;

  f32x4 acc[4][4] = {};

  for (int kt = k0; kt < k0 + kchunk; kt += 64) {
    #pragma unroll
    for (int r = 0; r < 4; ++r)
      gload_lds16(A + (size_t)(brow * 128 + r * 32 + srow) * NM + kt + scol,
                  (char*)As + r * 4096 + wv * 1024);
    #pragma unroll
    for (int r = 0; r < 4; ++r)
      gload_lds16(Bt + (size_t)(bcol * 128 + r * 32 + srow) * NM + kt + scol,
                  (char*)Bs + r * 4096 + wv * 1024);
    __syncthreads();
    #pragma unroll
    for (int kk = 0; kk < 2; ++kk) {
      bf16x8 a[4], b[4];
      #pragma unroll
      for (int m = 0; m < 4; ++m)
        a[m] = *(const bf16x8*)(As + (wr * 64 + m * 16 + lr15) * 64 + kk * 32 + lhi * 8);
      #pragma unroll
      for (int n = 0; n < 4; ++n)
        b[n] = *(const bf16x8*)(Bs + (wc * 64 + n * 16 + lr15) * 64 + kk * 32 + lhi * 8);
      #pragma unroll
      for (int m = 0; m < 4; ++m)
        #pragma unroll
        for (int n = 0; n < 4; ++n)
          acc[m][n] = __builtin_amdgcn_mfma_f32_16x16x32_bf16(a[m], b[n], acc[m][n], 0, 0, 0);
    }
    __syncthreads();
  }
  float* Cp = part + (size_t)ksp * NB * ND;
  const int crow0 = brow * 128 + wr * 64 + lhi * 4;
  const int ccol0 = bcol * 128 + wc * 64 + lr15;
  #pragma unroll
  for (int m = 0; m < 4; ++m)
    #pragma unroll
    for (int n = 0; n < 4; ++n)
      #pragma unroll
      for (int j = 0; j < 4; ++j)
        Cp[(size_t)(crow0 + m * 16 + j) * ND + ccol0 + n * 16] = acc[m][n][j];
}

// ---- reduce partials: mf = sum_k part[k] --------------------------------
__global__ void reduce_kernel(const float4* __restrict__ part, float4* __restrict__ mf, int S) {
  const size_t n4 = (size_t)NB * ND / 4;
  for (size_t i = (size_t)blockIdx.x * blockDim.x + threadIdx.x; i < n4;
       i += (size_t)gridDim.x * blockDim.x) {
    float4 s = part[i];
    for (int k = 1; k < S; ++k) {
      float4 p = part[(size_t)k * n4 + i];
      s.x += p.x; s.y += p.y; s.z += p.z; s.w += p.w;
    }
    mf[i] = s;
  }
}

extern "C" void kernel_launch(void* const* d_in, const int* in_sizes, int n_in,
                              void* d_out, int out_size, void* d_ws, size_t ws_size,
                              hipStream_t stream) {
  const float* q   = (const float*)d_in[0];
  const float* mem = (const float*)d_in[1];
  float* mf   = (float*)d_out;                       // [4096 x 1024]
  float* attn = (float*)d_out + (size_t)NB * ND;     // [4096 x 8192]
  char* ws = (char*)d_ws;
  unsigned short* qn    = (unsigned short*)(ws);                      // 8 MiB
  unsigned short* memn  = (unsigned short*)(ws + ((size_t)8  << 20)); // 16 MiB
  unsigned short* memt  = (unsigned short*)(ws + ((size_t)24 << 20)); // 16 MiB
  unsigned short* attnb = (unsigned short*)(ws + ((size_t)40 << 20)); // 64 MiB
  float* part           = (float*)(ws + ((size_t)104 << 20));         // S x 16 MiB
  const bool useb = ws_size >= ((size_t)104 << 20);
  int S = 1;
  if (useb && ws_size > ((size_t)104 << 20)) {
    size_t avail = (ws_size - ((size_t)104 << 20)) / ((size_t)NB * ND * 4);
    S = avail >= 8 ? 8 : avail >= 4 ? 4 : avail >= 2 ? 2 : 1;
  }

  hipLaunchKernelGGL(nrm_kernel, dim3(NM), dim3(256), 0, stream, mem, memn);
  hipLaunchKernelGGL(nrm_kernel, dim3(NB), dim3(256), 0, stream, q, qn);
  hipLaunchKernelGGL(tr_kernel, dim3(ND / 64, NM / 64), dim3(256), 0, stream, memn, memt);
  // sim = qn * memn^T  -> fp32 into attn region (pre-softmax scratch)
  hipLaunchKernelGGL((gemm_kernel<true, true>), dim3((NB / 128) * (NM / 128)), dim3(256), 0,
                     stream, (const void*)qn, memn, attn, ND, NM, NB / 128);
  hipLaunchKernelGGL(softmax_kernel, dim3(NB), dim3(256), 0, stream, attn, attnb, useb ? 1 : 0);
  // mf = attn * memn
  if (useb && S >= 2) {
    hipLaunchKernelGGL(gemm_splitk_kernel, dim3(256 * S), dim3(256), 0, stream,
                       attnb, memt, part, NM / S);
    hipLaunchKernelGGL(reduce_kernel, dim3(2048), dim3(256), 0, stream,
                       (const float4*)part, (float4*)mf, S);
  } else if (useb) {
    hipLaunchKernelGGL((gemm_kernel<true, false>), dim3(NB / 128, ND / 128), dim3(256), 0,
                       stream, (const void*)attnb, memt, mf, NM, ND, NB / 128);
  } else {
    hipLaunchKernelGGL((gemm_kernel<false, false>), dim3(NB / 128, ND / 128), dim3(256), 0,
                       stream, (const void*)attn, memt, mf, NM, ND, NB / 128);
  }
}

// Round 3
// 236.600 us; speedup vs baseline: 1.3935x; 1.3935x over previous
//
#include <hip/hip_runtime.h>
#include <stdint.h>

#define NB 4096   // query rows
#define NM 8192   // memory rows
#define ND 1024   // feature dim

typedef __attribute__((ext_vector_type(8))) short bf16x8;
typedef __attribute__((ext_vector_type(4))) float f32x4;
typedef __attribute__((ext_vector_type(8))) unsigned short u16x8;

static __device__ __forceinline__ unsigned short f2bf(float f) {
  union { float f; uint32_t u; } v; v.f = f;
  uint32_t u = v.u;
  u += 0x7fffu + ((u >> 16) & 1u);   // RNE
  return (unsigned short)(u >> 16);
}

static __device__ __forceinline__ void gload_lds16(const void* g, void* l) {
  __builtin_amdgcn_global_load_lds(
      (__attribute__((address_space(1))) void*)g,
      (__attribute__((address_space(3))) void*)l, 16, 0, 0);
}

#define BAR()   __builtin_amdgcn_s_barrier()
#define SCB()   __builtin_amdgcn_sched_barrier(0)
#define LGKM0() asm volatile("s_waitcnt lgkmcnt(0)" ::: "memory")
#define VMC4()  asm volatile("s_waitcnt vmcnt(4)" ::: "memory")

// ---- L2-normalize rows of x [rows x 1024] fp32 -> bf16 out -----------------
__global__ void nrm_kernel(const float* __restrict__ x, unsigned short* __restrict__ out) {
  const int row = blockIdx.x, t = threadIdx.x;
  const float4 v = ((const float4*)(x + (size_t)row * ND))[t];
  float ss = v.x * v.x + v.y * v.y + v.z * v.z + v.w * v.w;
  #pragma unroll
  for (int o = 32; o > 0; o >>= 1) ss += __shfl_xor(ss, o);
  __shared__ float red[4];
  if ((t & 63) == 0) red[t >> 6] = ss;
  __syncthreads();
  ss = (red[0] + red[1]) + (red[2] + red[3]);
  const float sc = 1.0f / fmaxf(sqrtf(ss), 1e-12f);
  ushort4 o4;
  o4.x = f2bf(v.x * sc); o4.y = f2bf(v.y * sc);
  o4.z = f2bf(v.z * sc); o4.w = f2bf(v.w * sc);
  ((ushort4*)(out + (size_t)row * ND))[t] = o4;
}

// ---- transpose memn [8192x1024] bf16 -> memt [1024x8192] bf16 --------------
__global__ void tr_kernel(const unsigned short* __restrict__ memn, unsigned short* __restrict__ memt) {
  __shared__ unsigned short Ts[64][66];
  const int t = threadIdx.x;
  const int d0 = blockIdx.x * 64, m0 = blockIdx.y * 64;
  #pragma unroll
  for (int r = 0; r < 2; ++r) {
    const int lrow = r * 32 + (t >> 3);
    const int lcol = (t & 7) * 8;
    u16x8 v = *(const u16x8*)(memn + (size_t)(m0 + lrow) * ND + d0 + lcol);
    #pragma unroll
    for (int j = 0; j < 8; ++j) Ts[lcol + j][lrow] = v[j];
  }
  __syncthreads();
  #pragma unroll
  for (int r = 0; r < 2; ++r) {
    const int orow = r * 32 + (t >> 3);
    const int ocol = (t & 7) * 8;
    u16x8 o;
    #pragma unroll
    for (int j = 0; j < 8; ++j) o[j] = Ts[orow][ocol + j];
    *(u16x8*)(memt + (size_t)(d0 + orow) * NM + m0 + ocol) = o;
  }
}

// ---- row softmax in-place on sim [4096x8192] fp32; optional bf16 copy ------
__global__ void softmax_kernel(float* __restrict__ sim, unsigned short* __restrict__ attnb, int wb) {
  const int row = blockIdx.x, t = threadIdx.x;
  float* prow = sim + (size_t)row * NM;
  float4 v[8];
  #pragma unroll
  for (int i = 0; i < 8; ++i) v[i] = ((const float4*)prow)[i * 256 + t];
  float mx = -3.4e38f;
  #pragma unroll
  for (int i = 0; i < 8; ++i)
    mx = fmaxf(mx, fmaxf(fmaxf(v[i].x, v[i].y), fmaxf(v[i].z, v[i].w)));
  #pragma unroll
  for (int o = 32; o > 0; o >>= 1) mx = fmaxf(mx, __shfl_xor(mx, o));
  __shared__ float red[8];
  if ((t & 63) == 0) red[t >> 6] = mx;
  __syncthreads();
  mx = fmaxf(fmaxf(red[0], red[1]), fmaxf(red[2], red[3]));
  float s = 0.f;
  #pragma unroll
  for (int i = 0; i < 8; ++i) {
    v[i].x = __expf(v[i].x - mx); v[i].y = __expf(v[i].y - mx);
    v[i].z = __expf(v[i].z - mx); v[i].w = __expf(v[i].w - mx);
    s += (v[i].x + v[i].y) + (v[i].z + v[i].w);
  }
  #pragma unroll
  for (int o = 32; o > 0; o >>= 1) s += __shfl_xor(s, o);
  if ((t & 63) == 0) red[4 + (t >> 6)] = s;
  __syncthreads();
  s = (red[4] + red[5]) + (red[6] + red[7]);
  const float inv = 1.0f / s;
  #pragma unroll
  for (int i = 0; i < 8; ++i) {
    v[i].x *= inv; v[i].y *= inv; v[i].z *= inv; v[i].w *= inv;
    ((float4*)prow)[i * 256 + t] = v[i];
    if (wb) {
      ushort4 b;
      b.x = f2bf(v[i].x); b.y = f2bf(v[i].y); b.z = f2bf(v[i].z); b.w = f2bf(v[i].w);
      *(ushort4*)(attnb + (size_t)row * NM + (size_t)(i * 256 + t) * 4) = b;
    }
  }
}

// ======================= 256x256 8-phase GEMM (T2+T3+T4+T5) ==================
// C[M,N] = A[M,K] * B[N,K]^T (both bf16, row-major, ld = K stride).
// 512 threads = 8 waves (2 M x 4 N), per-wave 128x64 out, BK=64, dbuf LDS 128K.
// LDS XOR-swizzle: phys_cb = cb ^ ((row&7)<<4); applied on the global SOURCE
// of global_load_lds (linear dest, rule #21) and on ds_read addresses.
// Split-K: grid = tps * S; ksp = id/tps; C += ksp*cstride; k0 = ksp*kchunk.
extern "C" __global__ __launch_bounds__(512, 2) void gemm8p(
    const unsigned short* __restrict__ A, const unsigned short* __restrict__ B,
    float* __restrict__ C, int ld, int ldc, int mt, int tps, int kchunk,
    unsigned long long cstride)
{
  extern __shared__ char smem[];   // [buf][A 32K | B 32K] x2 = 128 KiB
  const int t = threadIdx.x;
  const int w = t >> 6, l = t & 63;
  const int wr = w >> 2, wc = w & 3;
  const int nwg = gridDim.x, cpx = nwg >> 3;
  const int id = (blockIdx.x & 7) * cpx + (blockIdx.x >> 3);  // XCD swizzle
  const int ksp = id / tps, rem = id % tps;
  const int brow = rem % mt, bcol = rem / mt;
  const int k0 = ksp * kchunk;
  const int nt = kchunk >> 6;          // K-tiles (must be even)
  float* Cp = C + (unsigned long long)ksp * cstride;

  // staging constants: lane -> (row within 8-row group, swizzled col)
  const int srow = l >> 3;                       // 0..7
  const int scol = ((l & 7) ^ srow) << 3;        // element col, 16B aligned
  // frag-read constants
  const int lr = l & 15, lhi = l >> 4;
  const int swz = (l & 7) << 4;
  const int cbk0 = (lhi * 16) ^ swz;             // byte col, kk=0
  const int cbk1 = (64 + lhi * 16) ^ swz;        // byte col, kk=1
  const int aoffr = (wr * 128 + lr) * 128;
  const int boffr = (wc * 64 + lr) * 128;

  const unsigned short* Ab = A + (size_t)(brow * 256 + w * 8 + srow) * ld + k0 + scol;
  const unsigned short* Bb = B + (size_t)(bcol * 256 + w * 8 + srow) * ld + k0 + scol;

  // stage one half-tile (2 x global_load_lds per wave)
  auto stageA = [&](int p, int h, int tau) {
    const int kt = (tau < nt ? tau : nt - 1) << 6;
    const unsigned short* g = Ab + (size_t)(h * 128) * ld + kt;
    char* d = smem + p * 65536 + h * 16384 + w * 1024;
    gload_lds16(g, d);
    gload_lds16(g + (size_t)64 * ld, d + 8192);
  };
  auto stageB = [&](int p, int h, int tau) {
    const int kt = (tau < nt ? tau : nt - 1) << 6;
    const unsigned short* g = Bb + (size_t)(h * 128) * ld + kt;
    char* d = smem + p * 65536 + 32768 + h * 16384 + w * 1024;
    gload_lds16(g, d);
    gload_lds16(g + (size_t)64 * ld, d + 8192);
  };
  auto ldA = [&](int p, int m, int kk) -> bf16x8 {
    return *(const bf16x8*)(smem + p * 65536 + aoffr + m * 2048 + (kk ? cbk1 : cbk0));
  };
  auto ldB = [&](int p, int nf, int kk) -> bf16x8 {
    return *(const bf16x8*)(smem + p * 65536 + 32768 + boffr + nf * 2048 + (kk ? cbk1 : cbk0));
  };

  f32x4 acc[8][4] = {};

  // prologue: tile0 (A+B) + tile1 (B); tile1's A comes in phases 1-2.
  stageB(0, 0, 0); stageB(0, 1, 0);
  stageA(0, 0, 0); stageA(0, 1, 0);
  stageB(1, 0, 1); stageB(1, 1, 1);
  VMC4(); SCB();
  BAR(); SCB();

  const int niter = nt >> 1;
  for (int i = 0; i < niter; ++i) {
    const int t1 = 2 * i + 1, t2 = 2 * i + 2, t3 = 2 * i + 3;
    bf16x8 alo[4][2], ahi[4][2], blo[2][2], bhi[2][2];
    #pragma unroll
    for (int p = 0; p < 2; ++p) {   // p=0: tile 2i (buf0); p=1: tile 2i+1 (buf1)
      // ---- phase A: quad (m0-3, n0-1) : 12 ds_reads
      #pragma unroll
      for (int m = 0; m < 4; ++m) { alo[m][0] = ldA(p, m, 0); alo[m][1] = ldA(p, m, 1); }
      #pragma unroll
      for (int n = 0; n < 2; ++n) { blo[n][0] = ldB(p, n, 0); blo[n][1] = ldB(p, n, 1); }
      if (p == 0) stageA(1, 0, t1); else stageA(0, 0, t2);
      BAR(); LGKM0(); SCB();
      __builtin_amdgcn_s_setprio(1);
      #pragma unroll
      for (int m = 0; m < 4; ++m)
        #pragma unroll
        for (int n = 0; n < 2; ++n)
          #pragma unroll
          for (int kk = 0; kk < 2; ++kk)
            acc[m][n] = __builtin_amdgcn_mfma_f32_16x16x32_bf16(alo[m][kk], blo[n][kk], acc[m][n], 0, 0, 0);
      __builtin_amdgcn_s_setprio(0); SCB();
      BAR(); SCB();
      // ---- phase B: quad (m0-3, n2-3) : 4 ds_reads
      #pragma unroll
      for (int n = 0; n < 2; ++n) { bhi[n][0] = ldB(p, 2 + n, 0); bhi[n][1] = ldB(p, 2 + n, 1); }
      if (p == 0) stageA(1, 1, t1); else stageA(0, 1, t2);
      BAR(); LGKM0(); SCB();
      __builtin_amdgcn_s_setprio(1);
      #pragma unroll
      for (int m = 0; m < 4; ++m)
        #pragma unroll
        for (int n = 0; n < 2; ++n)
          #pragma unroll
          for (int kk = 0; kk < 2; ++kk)
            acc[m][2 + n] = __builtin_amdgcn_mfma_f32_16x16x32_bf16(alo[m][kk], bhi[n][kk], acc[m][2 + n], 0, 0, 0);
      __builtin_amdgcn_s_setprio(0); SCB();
      BAR(); SCB();
      // ---- phase C: quad (m4-7, n0-1) : 8 ds_reads (blo reused)
      #pragma unroll
      for (int m = 0; m < 4; ++m) { ahi[m][0] = ldA(p, 4 + m, 0); ahi[m][1] = ldA(p, 4 + m, 1); }
      if (p == 0) stageB(0, 0, t2); else stageB(1, 0, t3);
      BAR(); LGKM0(); SCB();
      __builtin_amdgcn_s_setprio(1);
      #pragma unroll
      for (int m = 0; m < 4; ++m)
        #pragma unroll
        for (int n = 0; n < 2; ++n)
          #pragma unroll
          for (int kk = 0; kk < 2; ++kk)
            acc[4 + m][n] = __builtin_amdgcn_mfma_f32_16x16x32_bf16(ahi[m][kk], blo[n][kk], acc[4 + m][n], 0, 0, 0);
      __builtin_amdgcn_s_setprio(0); SCB();
      BAR(); SCB();
      // ---- phase D: quad (m4-7, n2-3) : 0 ds_reads; counted vmcnt
      if (p == 0) stageB(0, 1, t2); else stageB(1, 1, t3);
      BAR(); LGKM0(); SCB();
      __builtin_amdgcn_s_setprio(1);
      #pragma unroll
      for (int m = 0; m < 4; ++m)
        #pragma unroll
        for (int n = 0; n < 2; ++n)
          #pragma unroll
          for (int kk = 0; kk < 2; ++kk)
            acc[4 + m][2 + n] = __builtin_amdgcn_mfma_f32_16x16x32_bf16(ahi[m][kk], bhi[n][kk], acc[4 + m][2 + n], 0, 0, 0);
      __builtin_amdgcn_s_setprio(0); SCB();
      VMC4(); SCB();
      BAR(); SCB();
    }
  }

  // epilogue: C/D map col=lane&15, row=(lane>>4)*4+j  [m89/m91]
  const int crow0 = brow * 256 + wr * 128 + lhi * 4;
  const int ccol0 = bcol * 256 + wc * 64 + lr;
  #pragma unroll
  for (int m = 0; m < 8; ++m)
    #pragma unroll
    for (int n = 0; n < 4; ++n)
      #pragma unroll
      for (int j = 0; j < 4; ++j)
        Cp[(size_t)(crow0 + m * 16 + j) * ldc + ccol0 + n * 16] = acc[m][n][j];
}

// ---- fallback 128^2 2-phase GEMM (round-1 validated) -----------------------
template<bool A_BF16>
__global__ __launch_bounds__(256) void gemm_kernel(
    const void* __restrict__ Ap, const unsigned short* __restrict__ Bt,
    float* __restrict__ C, int Kdim, int Ndim, int mt)
{
  __shared__ __align__(16) unsigned short As[128 * 64];
  __shared__ __align__(16) unsigned short Bs[128 * 64];
  const int t = threadIdx.x;
  const int wv = t >> 6, l = t & 63;
  const int wrk = wv >> 1, wck = wv & 1;
  const int brow = blockIdx.x, bcol = blockIdx.y;
  const int srow = t >> 3, scol = (t & 7) * 8;
  const int lr15 = l & 15, lhi = l >> 4;
  f32x4 acc[4][4] = {};
  for (int kt = 0; kt < Kdim; kt += 64) {
    if constexpr (A_BF16) {
      const unsigned short* A = (const unsigned short*)Ap;
      #pragma unroll
      for (int r = 0; r < 4; ++r)
        gload_lds16(A + (size_t)(brow * 128 + r * 32 + srow) * Kdim + kt + scol,
                    (char*)As + r * 4096 + wv * 1024);
    } else {
      const float* A = (const float*)Ap;
      #pragma unroll
      for (int r = 0; r < 8; ++r) {
        const int idx4 = r * 256 + t;
        const int row = idx4 >> 4, c4 = (idx4 & 15) * 4;
        float4 fv = *(const float4*)(A + (size_t)(brow * 128 + row) * Kdim + kt + c4);
        ushort4 b;
        b.x = f2bf(fv.x); b.y = f2bf(fv.y); b.z = f2bf(fv.z); b.w = f2bf(fv.w);
        *(ushort4*)(As + row * 64 + c4) = b;
      }
    }
    #pragma unroll
    for (int r = 0; r < 4; ++r)
      gload_lds16(Bt + (size_t)(bcol * 128 + r * 32 + srow) * Kdim + kt + scol,
                  (char*)Bs + r * 4096 + wv * 1024);
    __syncthreads();
    #pragma unroll
    for (int kk = 0; kk < 2; ++kk) {
      bf16x8 a[4], b[4];
      #pragma unroll
      for (int m = 0; m < 4; ++m)
        a[m] = *(const bf16x8*)(As + (wrk * 64 + m * 16 + lr15) * 64 + kk * 32 + lhi * 8);
      #pragma unroll
      for (int n = 0; n < 4; ++n)
        b[n] = *(const bf16x8*)(Bs + (wck * 64 + n * 16 + lr15) * 64 + kk * 32 + lhi * 8);
      #pragma unroll
      for (int m = 0; m < 4; ++m)
        #pragma unroll
        for (int n = 0; n < 4; ++n)
          acc[m][n] = __builtin_amdgcn_mfma_f32_16x16x32_bf16(a[m], b[n], acc[m][n], 0, 0, 0);
    }
    __syncthreads();
  }
  const int crow0 = brow * 128 + wrk * 64 + lhi * 4;
  const int ccol0 = bcol * 128 + wck * 64 + lr15;
  #pragma unroll
  for (int m = 0; m < 4; ++m)
    #pragma unroll
    for (int n = 0; n < 4; ++n)
      #pragma unroll
      for (int j = 0; j < 4; ++j)
        C[(size_t)(crow0 + m * 16 + j) * Ndim + ccol0 + n * 16] = acc[m][n][j];
}

// ---- reduce partials: mf = sum_k part[k] -----------------------------------
__global__ void reduce_kernel(const float4* __restrict__ part, float4* __restrict__ mf, int S) {
  const size_t n4 = (size_t)NB * ND / 4;
  for (size_t i = (size_t)blockIdx.x * blockDim.x + threadIdx.x; i < n4;
       i += (size_t)gridDim.x * blockDim.x) {
    float4 s = part[i];
    for (int k = 1; k < S; ++k) {
      float4 p = part[(size_t)k * n4 + i];
      s.x += p.x; s.y += p.y; s.z += p.z; s.w += p.w;
    }
    mf[i] = s;
  }
}

extern "C" void kernel_launch(void* const* d_in, const int* in_sizes, int n_in,
                              void* d_out, int out_size, void* d_ws, size_t ws_size,
                              hipStream_t stream) {
  const float* q   = (const float*)d_in[0];
  const float* mem = (const float*)d_in[1];
  float* mf   = (float*)d_out;                       // [4096 x 1024]
  float* attn = (float*)d_out + (size_t)NB * ND;     // [4096 x 8192]
  char* ws = (char*)d_ws;
  unsigned short* qn    = (unsigned short*)(ws);                      // 8 MiB
  unsigned short* memn  = (unsigned short*)(ws + ((size_t)8  << 20)); // 16 MiB
  unsigned short* memt  = (unsigned short*)(ws + ((size_t)24 << 20)); // 16 MiB
  unsigned short* attnb = (unsigned short*)(ws + ((size_t)40 << 20)); // 64 MiB
  float* part           = (float*)(ws + ((size_t)104 << 20));         // S x 16 MiB
  const int S = 4;
  const bool useb = ws_size >= (((size_t)104 << 20) + (size_t)S * NB * ND * 4);

  hipFuncSetAttribute((const void*)gemm8p,
                      hipFuncAttributeMaxDynamicSharedMemorySize, 131072);

  hipLaunchKernelGGL(nrm_kernel, dim3(NM), dim3(256), 0, stream, mem, memn);
  hipLaunchKernelGGL(nrm_kernel, dim3(NB), dim3(256), 0, stream, q, qn);
  hipLaunchKernelGGL(tr_kernel, dim3(ND / 64, NM / 64), dim3(256), 0, stream, memn, memt);

  // sim = qn * memn^T : M=4096, N=8192, K=1024. grid 16x32=512 tiles.
  hipLaunchKernelGGL(gemm8p, dim3((NB / 256) * (NM / 256)), dim3(512), 131072, stream,
                     qn, memn, attn, ND, NM, NB / 256, (NB / 256) * (NM / 256), ND, 0ULL);

  hipLaunchKernelGGL(softmax_kernel, dim3(NB), dim3(256), 0, stream, attn, attnb, useb ? 1 : 0);

  if (useb) {
    // mf = attnb * memt^T : M=4096, N=1024, K=8192, split-K S=4 (kchunk 2048).
    const int tps = (NB / 256) * (ND / 256);   // 16*4 = 64
    hipLaunchKernelGGL(gemm8p, dim3(tps * S), dim3(512), 131072, stream,
                       attnb, memt, part, NM, ND, NB / 256, tps, NM / S,
                       (unsigned long long)NB * ND);
    hipLaunchKernelGGL(reduce_kernel, dim3(2048), dim3(256), 0, stream,
                       (const float4*)part, (float4*)mf, S);
  } else {
    hipLaunchKernelGGL((gemm_kernel<false>), dim3(NB / 128, ND / 128), dim3(256), 0,
                       stream, (const void*)attn, memt, mf, NM, ND, NB / 128);
  }
}

// Round 4
// 221.353 us; speedup vs baseline: 1.4895x; 1.0689x over previous
//
#include <hip/hip_runtime.h>
#include <stdint.h>

#define NB 4096   // query rows
#define NM 8192   // memory rows
#define ND 1024   // feature dim

typedef __attribute__((ext_vector_type(8))) short bf16x8;
typedef __attribute__((ext_vector_type(4))) float f32x4;
typedef __attribute__((ext_vector_type(8))) unsigned short u16x8;

static __device__ __forceinline__ unsigned short f2bf(float f) {
  union { float f; uint32_t u; } v; v.f = f;
  uint32_t u = v.u;
  u += 0x7fffu + ((u >> 16) & 1u);   // RNE
  return (unsigned short)(u >> 16);
}
static __device__ __forceinline__ float bf2f(unsigned short b) {
  union { uint32_t u; float f; } v; v.u = ((uint32_t)b) << 16; return v.f;
}

static __device__ __forceinline__ void gload_lds16(const void* g, void* l) {
  __builtin_amdgcn_global_load_lds(
      (__attribute__((address_space(1))) void*)g,
      (__attribute__((address_space(3))) void*)l, 16, 0, 0);
}

#define BAR()   __builtin_amdgcn_s_barrier()
#define SCB()   __builtin_amdgcn_sched_barrier(0)
#define LGKM0() asm volatile("s_waitcnt lgkmcnt(0)" ::: "memory")
#define LGKM8() asm volatile("s_waitcnt lgkmcnt(8)" ::: "memory")
#define VMC8()  asm volatile("s_waitcnt vmcnt(8)" ::: "memory")

// ---- L2-normalize rows of x [rows x 1024] fp32 -> bf16 out -----------------
__global__ void nrm_kernel(const float* __restrict__ x, unsigned short* __restrict__ out) {
  const int row = blockIdx.x, t = threadIdx.x;
  const float4 v = ((const float4*)(x + (size_t)row * ND))[t];
  float ss = v.x * v.x + v.y * v.y + v.z * v.z + v.w * v.w;
  #pragma unroll
  for (int o = 32; o > 0; o >>= 1) ss += __shfl_xor(ss, o);
  __shared__ float red[4];
  if ((t & 63) == 0) red[t >> 6] = ss;
  __syncthreads();
  ss = (red[0] + red[1]) + (red[2] + red[3]);
  const float sc = 1.0f / fmaxf(sqrtf(ss), 1e-12f);
  ushort4 o4;
  o4.x = f2bf(v.x * sc); o4.y = f2bf(v.y * sc);
  o4.z = f2bf(v.z * sc); o4.w = f2bf(v.w * sc);
  ((ushort4*)(out + (size_t)row * ND))[t] = o4;
}

// ---- transpose memn [8192x1024] bf16 -> memt [1024x8192] bf16 --------------
__global__ void tr_kernel(const unsigned short* __restrict__ memn, unsigned short* __restrict__ memt) {
  __shared__ unsigned short Ts[64][66];
  const int t = threadIdx.x;
  const int d0 = blockIdx.x * 64, m0 = blockIdx.y * 64;
  #pragma unroll
  for (int r = 0; r < 2; ++r) {
    const int lrow = r * 32 + (t >> 3);
    const int lcol = (t & 7) * 8;
    u16x8 v = *(const u16x8*)(memn + (size_t)(m0 + lrow) * ND + d0 + lcol);
    #pragma unroll
    for (int j = 0; j < 8; ++j) Ts[lcol + j][lrow] = v[j];
  }
  __syncthreads();
  #pragma unroll
  for (int r = 0; r < 2; ++r) {
    const int orow = r * 32 + (t >> 3);
    const int ocol = (t & 7) * 8;
    u16x8 o;
    #pragma unroll
    for (int j = 0; j < 8; ++j) o[j] = Ts[orow][ocol + j];
    *(u16x8*)(memt + (size_t)(d0 + orow) * NM + m0 + ocol) = o;
  }
}

// ---- row softmax: read bf16 sim (in simb), write attn fp32 + attnb bf16 ----
// simb and attnb are the SAME buffer (in-place: each thread owns its elems).
__global__ void softmax_kernel(unsigned short* __restrict__ simb,
                               float* __restrict__ attn) {
  const int row = blockIdx.x, t = threadIdx.x;   // 256 thr, 32 elems each
  unsigned short* prow = simb + (size_t)row * NM;
  float v[32];
  #pragma unroll
  for (int i = 0; i < 4; ++i) {
    u16x8 bv = ((const u16x8*)prow)[i * 256 + t];
    #pragma unroll
    for (int j = 0; j < 8; ++j) v[i * 8 + j] = bf2f(bv[j]);
  }
  float mx = -3.4e38f;
  #pragma unroll
  for (int i = 0; i < 32; ++i) mx = fmaxf(mx, v[i]);
  #pragma unroll
  for (int o = 32; o > 0; o >>= 1) mx = fmaxf(mx, __shfl_xor(mx, o));
  __shared__ float red[8];
  if ((t & 63) == 0) red[t >> 6] = mx;
  __syncthreads();
  mx = fmaxf(fmaxf(red[0], red[1]), fmaxf(red[2], red[3]));
  float s = 0.f;
  #pragma unroll
  for (int i = 0; i < 32; ++i) { v[i] = __expf(v[i] - mx); s += v[i]; }
  #pragma unroll
  for (int o = 32; o > 0; o >>= 1) s += __shfl_xor(s, o);
  if ((t & 63) == 0) red[4 + (t >> 6)] = s;
  __syncthreads();
  s = (red[4] + red[5]) + (red[6] + red[7]);
  const float inv = 1.0f / s;
  float* arow = attn + (size_t)row * NM;
  #pragma unroll
  for (int i = 0; i < 4; ++i) {
    u16x8 bo;
    float4 f0, f1;
    #pragma unroll
    for (int j = 0; j < 8; ++j) {
      const float a = v[i * 8 + j] * inv;
      bo[j] = f2bf(a);
      if (j < 4) (&f0.x)[j] = a; else (&f1.x)[j - 4] = a;
    }
    const int e = (i * 256 + t) * 8;
    *(float4*)(arow + e) = f0;
    *(float4*)(arow + e + 4) = f1;
    ((u16x8*)prow)[i * 256 + t] = bo;
  }
}

// ======================= 256x256 8-phase GEMM (T2+T3+T4+T5) ==================
// C[M,N] = A[M,K] * B[N,K]^T (both bf16 row-major, ld = K stride).
// 512 thr = 8 waves (2M x 4N), per-wave 128x64 out, BK=64, dbuf LDS 128 KiB.
// Swizzle: phys_cb = cb ^ ((row&7)<<4), applied on the pre-swizzled global
// SOURCE of global_load_lds (linear dest, rule #21) and on ds_read addrs.
// Stage schedule (4-5 phase prefetch depth, single vmcnt(8)/tile):
//   T.ph3: B-h0(T+2);  T.ph4: B-h1(T+2), A-h0(T+2), A-h1(T+2); vmcnt(8).
// Region liveness: B(buf) free after T.ph2, A(buf) free after T.ph3.
// Split-K: grid = tps*S; ksp = id/tps; C += ksp*cstride; k0 = ksp*kchunk.
template<int CBF>
__global__ __launch_bounds__(512, 2) void gemm8p(
    const unsigned short* __restrict__ A, const unsigned short* __restrict__ B,
    void* __restrict__ Cv, int ld, int ldc, int mt, int tps, int kchunk,
    unsigned long long cstride)
{
  extern __shared__ char smem[];   // [buf][A 32K | B 32K] x2 = 128 KiB
  const int t = threadIdx.x;
  const int w = t >> 6, l = t & 63;
  const int wr = w >> 2, wc = w & 3;
  const int nwg = gridDim.x, cpx = nwg >> 3;
  const int id = (blockIdx.x & 7) * cpx + (blockIdx.x >> 3);  // XCD swizzle
  const int ksp = id / tps, rem = id % tps;
  const int brow = rem % mt, bcol = rem / mt;
  const int k0 = ksp * kchunk;
  const int nt = kchunk >> 6;          // K-tiles (even)

  const int srow = l >> 3;                       // staging row-in-8-group
  const int scol = ((l & 7) ^ srow) << 3;        // pre-swizzled global col
  const int lr = l & 15, lhi = l >> 4;
  const int swz = (l & 7) << 4;
  const int cbk0 = (lhi * 16) ^ swz;
  const int cbk1 = (64 + lhi * 16) ^ swz;
  const int aoffr = (wr * 128 + lr) * 128;
  const int boffr = (wc * 64 + lr) * 128;

  const unsigned short* Ab = A + (size_t)(brow * 256 + w * 8 + srow) * ld + k0 + scol;
  const unsigned short* Bb = B + (size_t)(bcol * 256 + w * 8 + srow) * ld + k0 + scol;

  auto stageA = [&](int p, int h, int tau) {
    const int kt = (tau < nt ? tau : nt - 1) << 6;
    const unsigned short* g = Ab + (size_t)(h * 128) * ld + kt;
    char* d = smem + p * 65536 + h * 16384 + w * 1024;
    gload_lds16(g, d);
    gload_lds16(g + (size_t)64 * ld, d + 8192);
  };
  auto stageB = [&](int p, int h, int tau) {
    const int kt = (tau < nt ? tau : nt - 1) << 6;
    const unsigned short* g = Bb + (size_t)(h * 128) * ld + kt;
    char* d = smem + p * 65536 + 32768 + h * 16384 + w * 1024;
    gload_lds16(g, d);
    gload_lds16(g + (size_t)64 * ld, d + 8192);
  };
  auto ldA = [&](int p, int m, int kk) -> bf16x8 {
    return *(const bf16x8*)(smem + p * 65536 + aoffr + m * 2048 + (kk ? cbk1 : cbk0));
  };
  auto ldB = [&](int p, int nf, int kk) -> bf16x8 {
    return *(const bf16x8*)(smem + p * 65536 + 32768 + boffr + nf * 2048 + (kk ? cbk1 : cbk0));
  };

  f32x4 acc[8][4] = {};

  // prologue: tiles 0 and 1 fully staged; drain tile0, leave tile1 in flight.
  stageB(0, 0, 0); stageB(0, 1, 0); stageA(0, 0, 0); stageA(0, 1, 0);
  stageB(1, 0, 1); stageB(1, 1, 1); stageA(1, 0, 1); stageA(1, 1, 1);
  VMC8(); SCB();
  BAR(); SCB();

  auto tile_body = [&](int p, int tau2) {
    bf16x8 alo[4][2], ahi[4][2], blo[2][2], bhi[2][2];
    // ---- ph1: quad (m0-3, n0-1); 12 ds_reads, no stage
    #pragma unroll
    for (int m = 0; m < 4; ++m) { alo[m][0] = ldA(p, m, 0); alo[m][1] = ldA(p, m, 1); }
    #pragma unroll
    for (int n = 0; n < 2; ++n) { blo[n][0] = ldB(p, n, 0); blo[n][1] = ldB(p, n, 1); }
    LGKM8(); SCB();
    BAR(); LGKM0(); SCB();
    __builtin_amdgcn_s_setprio(1);
    #pragma unroll
    for (int m = 0; m < 4; ++m)
      #pragma unroll
      for (int n = 0; n < 2; ++n)
        #pragma unroll
        for (int kk = 0; kk < 2; ++kk)
          acc[m][n] = __builtin_amdgcn_mfma_f32_16x16x32_bf16(alo[m][kk], blo[n][kk], acc[m][n], 0, 0, 0);
    __builtin_amdgcn_s_setprio(0); SCB();
    BAR(); SCB();
    // ---- ph2: quad (m0-3, n2-3); 4 ds_reads
    #pragma unroll
    for (int n = 0; n < 2; ++n) { bhi[n][0] = ldB(p, 2 + n, 0); bhi[n][1] = ldB(p, 2 + n, 1); }
    BAR(); LGKM0(); SCB();
    __builtin_amdgcn_s_setprio(1);
    #pragma unroll
    for (int m = 0; m < 4; ++m)
      #pragma unroll
      for (int n = 0; n < 2; ++n)
        #pragma unroll
        for (int kk = 0; kk < 2; ++kk)
          acc[m][2 + n] = __builtin_amdgcn_mfma_f32_16x16x32_bf16(alo[m][kk], bhi[n][kk], acc[m][2 + n], 0, 0, 0);
    __builtin_amdgcn_s_setprio(0); SCB();
    BAR(); SCB();
    // ---- ph3: quad (m4-7, n0-1); 8 ds_reads; stage B-h0(T+2) (B free aft ph2)
    #pragma unroll
    for (int m = 0; m < 4; ++m) { ahi[m][0] = ldA(p, 4 + m, 0); ahi[m][1] = ldA(p, 4 + m, 1); }
    stageB(p, 0, tau2);
    BAR(); LGKM0(); SCB();
    __builtin_amdgcn_s_setprio(1);
    #pragma unroll
    for (int m = 0; m < 4; ++m)
      #pragma unroll
      for (int n = 0; n < 2; ++n)
        #pragma unroll
        for (int kk = 0; kk < 2; ++kk)
          acc[4 + m][n] = __builtin_amdgcn_mfma_f32_16x16x32_bf16(ahi[m][kk], blo[n][kk], acc[4 + m][n], 0, 0, 0);
    __builtin_amdgcn_s_setprio(0); SCB();
    BAR(); SCB();
    // ---- ph4: quad (m4-7, n2-3); stage B-h1,A-h0,A-h1(T+2) (A free aft ph3)
    stageB(p, 1, tau2); stageA(p, 0, tau2); stageA(p, 1, tau2);
    BAR(); SCB();
    __builtin_amdgcn_s_setprio(1);
    #pragma unroll
    for (int m = 0; m < 4; ++m)
      #pragma unroll
      for (int n = 0; n < 2; ++n)
        #pragma unroll
        for (int kk = 0; kk < 2; ++kk)
          acc[4 + m][2 + n] = __builtin_amdgcn_mfma_f32_16x16x32_bf16(ahi[m][kk], bhi[n][kk], acc[4 + m][2 + n], 0, 0, 0);
    __builtin_amdgcn_s_setprio(0); SCB();
    VMC8(); SCB();          // drains tile T+1 (issued 4-5 phases ago)
    BAR(); SCB();
  };

  const int niter = nt >> 1;
  for (int i = 0; i < niter; ++i) {
    tile_body(0, 2 * i + 2);
    tile_body(1, 2 * i + 3);
  }

  // epilogue: C/D map col=lane&15, row=(lane>>4)*4+j  [m89/m91]
  const int crow0 = brow * 256 + wr * 128 + lhi * 4;
  const int ccol0 = bcol * 256 + wc * 64 + lr;
  if constexpr (CBF) {
    unsigned short* Cp = (unsigned short*)Cv + (unsigned long long)ksp * cstride;
    #pragma unroll
    for (int m = 0; m < 8; ++m)
      #pragma unroll
      for (int n = 0; n < 4; ++n)
        #pragma unroll
        for (int j = 0; j < 4; ++j)
          Cp[(size_t)(crow0 + m * 16 + j) * ldc + ccol0 + n * 16] = f2bf(acc[m][n][j]);
  } else {
    float* Cp = (float*)Cv + (unsigned long long)ksp * cstride;
    #pragma unroll
    for (int m = 0; m < 8; ++m)
      #pragma unroll
      for (int n = 0; n < 4; ++n)
        #pragma unroll
        for (int j = 0; j < 4; ++j)
          Cp[(size_t)(crow0 + m * 16 + j) * ldc + ccol0 + n * 16] = acc[m][n][j];
  }
}

// ---- reduce partials: mf = sum_k part[k] -----------------------------------
__global__ void reduce_kernel(const float4* __restrict__ part, float4* __restrict__ mf, int S) {
  const size_t n4 = (size_t)NB * ND / 4;
  for (size_t i = (size_t)blockIdx.x * blockDim.x + threadIdx.x; i < n4;
       i += (size_t)gridDim.x * blockDim.x) {
    float4 s = part[i];
    for (int k = 1; k < S; ++k) {
      float4 p = part[(size_t)k * n4 + i];
      s.x += p.x; s.y += p.y; s.z += p.z; s.w += p.w;
    }
    mf[i] = s;
  }
}

extern "C" void kernel_launch(void* const* d_in, const int* in_sizes, int n_in,
                              void* d_out, int out_size, void* d_ws, size_t ws_size,
                              hipStream_t stream) {
  const float* q   = (const float*)d_in[0];
  const float* mem = (const float*)d_in[1];
  float* mf   = (float*)d_out;                       // [4096 x 1024]
  float* attn = (float*)d_out + (size_t)NB * ND;     // [4096 x 8192]
  char* ws = (char*)d_ws;
  unsigned short* qn    = (unsigned short*)(ws);                      // 8 MiB
  unsigned short* memn  = (unsigned short*)(ws + ((size_t)8  << 20)); // 16 MiB
  unsigned short* memt  = (unsigned short*)(ws + ((size_t)24 << 20)); // 16 MiB
  unsigned short* simb  = (unsigned short*)(ws + ((size_t)40 << 20)); // 64 MiB (sim bf16 -> attnb)
  float* part           = (float*)(ws + ((size_t)104 << 20));         // S x 16 MiB
  const int S = 4;

  hipFuncSetAttribute((const void*)gemm8p<1>,
                      hipFuncAttributeMaxDynamicSharedMemorySize, 131072);
  hipFuncSetAttribute((const void*)gemm8p<0>,
                      hipFuncAttributeMaxDynamicSharedMemorySize, 131072);

  hipLaunchKernelGGL(nrm_kernel, dim3(NM), dim3(256), 0, stream, mem, memn);
  hipLaunchKernelGGL(nrm_kernel, dim3(NB), dim3(256), 0, stream, q, qn);
  hipLaunchKernelGGL(tr_kernel, dim3(ND / 64, NM / 64), dim3(256), 0, stream, memn, memt);

  // sim(bf16) = qn * memn^T : M=4096, N=8192, K=1024. grid 16x32 = 512 tiles.
  hipLaunchKernelGGL((gemm8p<1>), dim3((NB / 256) * (NM / 256)), dim3(512), 131072, stream,
                     qn, memn, (void*)simb, ND, NM, NB / 256,
                     (NB / 256) * (NM / 256), ND, 0ULL);

  // softmax: simb -> attn fp32 (d_out) + attnb bf16 (in place in simb)
  hipLaunchKernelGGL(softmax_kernel, dim3(NB), dim3(256), 0, stream, simb, attn);

  // mf = attnb * memt^T : M=4096, N=1024, K=8192, split-K S=4 (kchunk 2048).
  const int tps = (NB / 256) * (ND / 256);   // 16*4 = 64
  hipLaunchKernelGGL((gemm8p<0>), dim3(tps * S), dim3(512), 131072, stream,
                     simb, memt, (void*)part, NM, ND, NB / 256, tps, NM / S,
                     (unsigned long long)NB * ND);
  hipLaunchKernelGGL(reduce_kernel, dim3(2048), dim3(256), 0, stream,
                     (const float4*)part, (float4*)mf, S);
}

// Round 6
// 217.375 us; speedup vs baseline: 1.5167x; 1.0183x over previous
//
#include <hip/hip_runtime.h>
#include <stdint.h>

#define NB 4096   // query rows
#define NM 8192   // memory rows
#define ND 1024   // feature dim

typedef __attribute__((ext_vector_type(8))) short bf16x8;
typedef __attribute__((ext_vector_type(4))) float f32x4;
typedef __attribute__((ext_vector_type(8))) unsigned short u16x8;

static __device__ __forceinline__ unsigned short f2bf(float f) {
  union { float f; uint32_t u; } v; v.f = f;
  uint32_t u = v.u;
  u += 0x7fffu + ((u >> 16) & 1u);   // RNE
  return (unsigned short)(u >> 16);
}
static __device__ __forceinline__ float bf2f(unsigned short b) {
  union { uint32_t u; float f; } v; v.u = ((uint32_t)b) << 16; return v.f;
}

static __device__ __forceinline__ void gload_lds16(const void* g, void* l) {
  __builtin_amdgcn_global_load_lds(
      (__attribute__((address_space(1))) void*)g,
      (__attribute__((address_space(3))) void*)l, 16, 0, 0);
}

#define BAR()   __builtin_amdgcn_s_barrier()
#define SCB()   __builtin_amdgcn_sched_barrier(0)
#define LGKM0() asm volatile("s_waitcnt lgkmcnt(0)" ::: "memory")
#define LGKM8() asm volatile("s_waitcnt lgkmcnt(8)" ::: "memory")
#define VMC8()  asm volatile("s_waitcnt vmcnt(8)" ::: "memory")
#define VMC0()  asm volatile("s_waitcnt vmcnt(0)" ::: "memory")

// ---- L2-normalize rows of x [rows x 1024] fp32 -> bf16 out -----------------
__global__ void nrm_kernel(const float* __restrict__ x, unsigned short* __restrict__ out) {
  const int row = blockIdx.x, t = threadIdx.x;
  const float4 v = ((const float4*)(x + (size_t)row * ND))[t];
  float ss = v.x * v.x + v.y * v.y + v.z * v.z + v.w * v.w;
  #pragma unroll
  for (int o = 32; o > 0; o >>= 1) ss += __shfl_xor(ss, o);
  __shared__ float red[4];
  if ((t & 63) == 0) red[t >> 6] = ss;
  __syncthreads();
  ss = (red[0] + red[1]) + (red[2] + red[3]);
  const float sc = 1.0f / fmaxf(sqrtf(ss), 1e-12f);
  ushort4 o4;
  o4.x = f2bf(v.x * sc); o4.y = f2bf(v.y * sc);
  o4.z = f2bf(v.z * sc); o4.w = f2bf(v.w * sc);
  ((ushort4*)(out + (size_t)row * ND))[t] = o4;
}

// ---- transpose memn [8192x1024] bf16 -> memt [1024x8192] bf16 --------------
__global__ void tr_kernel(const unsigned short* __restrict__ memn, unsigned short* __restrict__ memt) {
  __shared__ unsigned short Ts[64][66];
  const int t = threadIdx.x;
  const int d0 = blockIdx.x * 64, m0 = blockIdx.y * 64;
  #pragma unroll
  for (int r = 0; r < 2; ++r) {
    const int lrow = r * 32 + (t >> 3);
    const int lcol = (t & 7) * 8;
    u16x8 v = *(const u16x8*)(memn + (size_t)(m0 + lrow) * ND + d0 + lcol);
    #pragma unroll
    for (int j = 0; j < 8; ++j) Ts[lcol + j][lrow] = v[j];
  }
  __syncthreads();
  #pragma unroll
  for (int r = 0; r < 2; ++r) {
    const int orow = r * 32 + (t >> 3);
    const int ocol = (t & 7) * 8;
    u16x8 o;
    #pragma unroll
    for (int j = 0; j < 8; ++j) o[j] = Ts[orow][ocol + j];
    *(u16x8*)(memt + (size_t)(d0 + orow) * NM + m0 + ocol) = o;
  }
}

// ======================= 256x256 8-phase GEMM (T2+T3+T4+T5) ==================
// C[M,N] = A[M,K] * B[N,K]^T (both bf16 row-major, ld = K stride).
// 512 thr = 8 waves (2M x 4N), per-wave 128x64 out, BK=64, dbuf LDS 128 KiB.
// Swizzle: phys_cb = cb ^ ((row&7)<<4), pre-swizzled global SOURCE for
// global_load_lds (linear dest, rule #21) + swizzled ds_read addrs.
// FRAGMENT ROW MAP (race fix, r5 post-mortem): A row = m*32 + wr*16 + lr,
// B row = nf*64 + wc*16 + lr. So for EVERY wave: alo(m0-3) reads A-h0 only,
// ahi reads A-h1 only, blo reads B-h0 only, bhi reads B-h1 only.
// Quadrant order ph1(alo*blo) ph2(ahi*blo) ph3(ahi*bhi) ph4(alo*bhi):
//   region last LDS-read: A-h0 ph1, B-h0 ph1, A-h1 ph2, B-h1 ph3
//   stage (T+2):          ph2: A-h0 + B-h0 (4 loads), ph3: A-h1, ph4: B-h1
// Each stage is >=1 end-barrier after its region's last read (reader's LGKM0
// precedes its barrier) -> no cross-wave write/read race.
// Single vmcnt(8) at ph4 end: drains T+1's 8 loads, leaves T+2's 8 in flight.
// MODE 0: fp32 C partials (split-K).  MODE 1: E=exp(C) bf16 + psum row-sums.
template<int MODE>
__global__ __launch_bounds__(512, 2) void gemm8p(
    const unsigned short* __restrict__ A, const unsigned short* __restrict__ B,
    void* __restrict__ Cv, float* __restrict__ psum,
    int ld, int ldc, int mt, int tps, int kchunk, unsigned long long cstride)
{
  extern __shared__ char smem[];   // [buf][A 32K | B 32K] x2 = 128 KiB
  const int t = threadIdx.x;
  const int w = t >> 6, l = t & 63;
  const int wr = w >> 2, wc = w & 3;
  const int nwg = gridDim.x, cpx = nwg >> 3;
  const int id = (blockIdx.x & 7) * cpx + (blockIdx.x >> 3);  // XCD swizzle
  const int ksp = id / tps, rem = id % tps;
  const int brow = rem % mt, bcol = rem / mt;
  const int k0 = ksp * kchunk;
  const int nt = kchunk >> 6;          // K-tiles (even)

  const int srow = l >> 3;                       // staging row-in-8-group
  const int scol = ((l & 7) ^ srow) << 3;        // pre-swizzled global col
  const int lr = l & 15, lhi = l >> 4;
  const int swz = (l & 7) << 4;
  const int cbk0 = (lhi * 16) ^ swz;
  const int cbk1 = (64 + lhi * 16) ^ swz;
  const int aoffr = (wr * 16 + lr) * 128;        // + m*4096
  const int boffr = (wc * 16 + lr) * 128;        // + nf*8192

  const unsigned short* Ab = A + (size_t)(brow * 256 + w * 8 + srow) * ld + k0 + scol;
  const unsigned short* Bb = B + (size_t)(bcol * 256 + w * 8 + srow) * ld + k0 + scol;

  auto stageA = [&](int p, int h, int tau) {
    const int kt = (tau < nt ? tau : nt - 1) << 6;
    const unsigned short* g = Ab + (size_t)(h * 128) * ld + kt;
    char* d = smem + p * 65536 + h * 16384 + w * 1024;
    gload_lds16(g, d);
    gload_lds16(g + (size_t)64 * ld, d + 8192);
  };
  auto stageB = [&](int p, int h, int tau) {
    const int kt = (tau < nt ? tau : nt - 1) << 6;
    const unsigned short* g = Bb + (size_t)(h * 128) * ld + kt;
    char* d = smem + p * 65536 + 32768 + h * 16384 + w * 1024;
    gload_lds16(g, d);
    gload_lds16(g + (size_t)64 * ld, d + 8192);
  };
  auto ldA = [&](int p, int m, int kk) -> bf16x8 {   // A row m*32+wr*16+lr
    return *(const bf16x8*)(smem + p * 65536 + m * 4096 + aoffr + (kk ? cbk1 : cbk0));
  };
  auto ldB = [&](int p, int nf, int kk) -> bf16x8 {  // B row nf*64+wc*16+lr
    return *(const bf16x8*)(smem + p * 65536 + 32768 + nf * 8192 + boffr + (kk ? cbk1 : cbk0));
  };

  f32x4 acc[8][4] = {};

  // prologue: tiles 0 and 1 fully staged; drain tile0, leave tile1 in flight.
  stageB(0, 0, 0); stageB(0, 1, 0); stageA(0, 0, 0); stageA(0, 1, 0);
  stageB(1, 0, 1); stageB(1, 1, 1); stageA(1, 0, 1); stageA(1, 1, 1);
  VMC8(); SCB();
  BAR(); SCB();

  auto tile_body = [&](int p, int tau2) {
    bf16x8 alo[4][2], ahi[4][2], blo[2][2], bhi[2][2];
    // ---- ph1: (alo, blo) -> acc[m][n]; 12 ds_reads, no stage
    #pragma unroll
    for (int m = 0; m < 4; ++m) { alo[m][0] = ldA(p, m, 0); alo[m][1] = ldA(p, m, 1); }
    #pragma unroll
    for (int n = 0; n < 2; ++n) { blo[n][0] = ldB(p, n, 0); blo[n][1] = ldB(p, n, 1); }
    LGKM8(); SCB();
    BAR(); LGKM0(); SCB();
    __builtin_amdgcn_s_setprio(1);
    #pragma unroll
    for (int m = 0; m < 4; ++m)
      #pragma unroll
      for (int n = 0; n < 2; ++n)
        #pragma unroll
        for (int kk = 0; kk < 2; ++kk)
          acc[m][n] = __builtin_amdgcn_mfma_f32_16x16x32_bf16(alo[m][kk], blo[n][kk], acc[m][n], 0, 0, 0);
    __builtin_amdgcn_s_setprio(0); SCB();
    BAR(); SCB();
    // ---- ph2: (ahi, blo) -> acc[4+m][n]; 8 ds_reads; stage A-h0 + B-h0 (T+2)
    #pragma unroll
    for (int m = 0; m < 4; ++m) { ahi[m][0] = ldA(p, 4 + m, 0); ahi[m][1] = ldA(p, 4 + m, 1); }
    stageA(p, 0, tau2); stageB(p, 0, tau2);
    BAR(); LGKM0(); SCB();
    __builtin_amdgcn_s_setprio(1);
    #pragma unroll
    for (int m = 0; m < 4; ++m)
      #pragma unroll
      for (int n = 0; n < 2; ++n)
        #pragma unroll
        for (int kk = 0; kk < 2; ++kk)
          acc[4 + m][n] = __builtin_amdgcn_mfma_f32_16x16x32_bf16(ahi[m][kk], blo[n][kk], acc[4 + m][n], 0, 0, 0);
    __builtin_amdgcn_s_setprio(0); SCB();
    BAR(); SCB();
    // ---- ph3: (ahi, bhi) -> acc[4+m][2+n]; 4 ds_reads; stage A-h1 (T+2)
    #pragma unroll
    for (int n = 0; n < 2; ++n) { bhi[n][0] = ldB(p, 2 + n, 0); bhi[n][1] = ldB(p, 2 + n, 1); }
    stageA(p, 1, tau2);
    BAR(); LGKM0(); SCB();
    __builtin_amdgcn_s_setprio(1);
    #pragma unroll
    for (int m = 0; m < 4; ++m)
      #pragma unroll
      for (int n = 0; n < 2; ++n)
        #pragma unroll
        for (int kk = 0; kk < 2; ++kk)
          acc[4 + m][2 + n] = __builtin_amdgcn_mfma_f32_16x16x32_bf16(ahi[m][kk], bhi[n][kk], acc[4 + m][2 + n], 0, 0, 0);
    __builtin_amdgcn_s_setprio(0); SCB();
    BAR(); SCB();
    // ---- ph4: (alo, bhi) -> acc[m][2+n]; 0 ds_reads; stage B-h1; vmcnt drain
    stageB(p, 1, tau2);
    BAR(); SCB();
    __builtin_amdgcn_s_setprio(1);
    #pragma unroll
    for (int m = 0; m < 4; ++m)
      #pragma unroll
      for (int n = 0; n < 2; ++n)
        #pragma unroll
        for (int kk = 0; kk < 2; ++kk)
          acc[m][2 + n] = __builtin_amdgcn_mfma_f32_16x16x32_bf16(alo[m][kk], bhi[n][kk], acc[m][2 + n], 0, 0, 0);
    __builtin_amdgcn_s_setprio(0); SCB();
    VMC8(); SCB();          // drains tile T+1 (issued last body)
    BAR(); SCB();
  };

  const int niter = nt >> 1;
  for (int i = 0; i < niter; ++i) {
    tile_body(0, 2 * i + 2);
    tile_body(1, 2 * i + 3);
  }

  // epilogue: C row = brow*256 + m*32 + wr*16 + lhi*4 + j,
  //           C col = bcol*256 + n*64 + wc*16 + lr     [m89/m91 C/D map]
  const int crow0 = brow * 256 + wr * 16 + lhi * 4;
  const int ccol0 = bcol * 256 + wc * 16 + lr;
  if constexpr (MODE == 1) {
    // E = exp(sim) bf16 + per-block row-sum partials (deterministic)
    unsigned short* Cp = (unsigned short*)Cv;
    float rs[8][4];
    #pragma unroll
    for (int m = 0; m < 8; ++m)
      #pragma unroll
      for (int j = 0; j < 4; ++j) rs[m][j] = 0.f;
    #pragma unroll
    for (int m = 0; m < 8; ++m)
      #pragma unroll
      for (int n = 0; n < 4; ++n)
        #pragma unroll
        for (int j = 0; j < 4; ++j) {
          const float e = __expf(acc[m][n][j]);
          rs[m][j] += e;
          Cp[(size_t)(crow0 + m * 32 + j) * ldc + ccol0 + n * 64] = f2bf(e);
        }
    // 16-lane (lr) reduce -> lanes lr==0 hold this wave's 64-col sums
    #pragma unroll
    for (int m = 0; m < 8; ++m)
      #pragma unroll
      for (int j = 0; j < 4; ++j)
        #pragma unroll
        for (int o = 1; o < 16; o <<= 1) rs[m][j] += __shfl_xor(rs[m][j], o);
    VMC0();            // in-flight dummy stages still write smem
    __syncthreads();
    float* ls = (float*)smem;   // [wc][256 rows] = 4 KiB (buffer-0 region)
    if (lr == 0) {
      #pragma unroll
      for (int m = 0; m < 8; ++m)
        #pragma unroll
        for (int j = 0; j < 4; ++j)
          ls[wc * 256 + wr * 16 + m * 32 + lhi * 4 + j] = rs[m][j];
    }
    __syncthreads();
    if (t < 256) {
      const float s4 = ls[t] + ls[256 + t] + ls[512 + t] + ls[768 + t];
      psum[(size_t)bcol * NB + brow * 256 + t] = s4;
    }
  } else {
    float* Cp = (float*)Cv + (unsigned long long)ksp * cstride;
    #pragma unroll
    for (int m = 0; m < 8; ++m)
      #pragma unroll
      for (int n = 0; n < 4; ++n)
        #pragma unroll
        for (int j = 0; j < 4; ++j)
          Cp[(size_t)(crow0 + m * 32 + j) * ldc + ccol0 + n * 64] = acc[m][n][j];
  }
}

// ---- scale: attn = E / s, s = sum of 32 col-block partials; also 1/s -------
__global__ void scale_kernel(const unsigned short* __restrict__ E,
                             const float* __restrict__ psum,
                             float* __restrict__ attn, float* __restrict__ sinv) {
  const int row = blockIdx.x, t = threadIdx.x;   // 256 thr
  __shared__ float sh;
  if (t < 64) {
    float p = (t < 32) ? psum[(size_t)t * NB + row] : 0.f;
    #pragma unroll
    for (int o = 16; o > 0; o >>= 1) p += __shfl_xor(p, o);
    if (t == 0) { sh = p; sinv[row] = 1.0f / p; }
  }
  __syncthreads();
  const float inv = 1.0f / sh;
  const unsigned short* erow = E + (size_t)row * NM;
  float* arow = attn + (size_t)row * NM;
  #pragma unroll
  for (int i = 0; i < 4; ++i) {
    u16x8 bv = ((const u16x8*)erow)[i * 256 + t];
    float4 f0, f1;
    #pragma unroll
    for (int j = 0; j < 8; ++j) {
      const float a = bf2f(bv[j]) * inv;
      if (j < 4) (&f0.x)[j] = a; else (&f1.x)[j - 4] = a;
    }
    const int e = (i * 256 + t) * 8;
    *(float4*)(arow + e) = f0;
    *(float4*)(arow + e + 4) = f1;
  }
}

// ---- reduce partials: mf = (sum_k part[k]) * sinv[row], S = 4 --------------
__global__ void reduce_kernel(const float4* __restrict__ part, float4* __restrict__ mf,
                              const float* __restrict__ sinv) {
  const size_t n4 = (size_t)NB * ND / 4;
  for (size_t i = (size_t)blockIdx.x * blockDim.x + threadIdx.x; i < n4;
       i += (size_t)gridDim.x * blockDim.x) {
    const float is = sinv[i >> 8];   // 256 float4 per row
    float4 s = part[i];
    #pragma unroll
    for (int k = 1; k < 4; ++k) {
      float4 p = part[(size_t)k * n4 + i];
      s.x += p.x; s.y += p.y; s.z += p.z; s.w += p.w;
    }
    s.x *= is; s.y *= is; s.z *= is; s.w *= is;
    mf[i] = s;
  }
}

extern "C" void kernel_launch(void* const* d_in, const int* in_sizes, int n_in,
                              void* d_out, int out_size, void* d_ws, size_t ws_size,
                              hipStream_t stream) {
  const float* q   = (const float*)d_in[0];
  const float* mem = (const float*)d_in[1];
  float* mf   = (float*)d_out;                       // [4096 x 1024]
  float* attn = (float*)d_out + (size_t)NB * ND;     // [4096 x 8192]
  char* ws = (char*)d_ws;
  unsigned short* qn   = (unsigned short*)(ws);                        // 8 MiB
  unsigned short* memn = (unsigned short*)(ws + ((size_t)8  << 20));   // 16 MiB
  unsigned short* memt = (unsigned short*)(ws + ((size_t)24 << 20));   // 16 MiB
  unsigned short* E    = (unsigned short*)(ws + ((size_t)40 << 20));   // 64 MiB
  float* psum          = (float*)(ws + ((size_t)104 << 20));           // 512 KiB
  float* sinv          = (float*)(ws + ((size_t)104 << 20) + (512 << 10)); // 16 KiB
  float* part          = (float*)(ws + ((size_t)105 << 20));           // 64 MiB

  hipFuncSetAttribute((const void*)gemm8p<1>,
                      hipFuncAttributeMaxDynamicSharedMemorySize, 131072);
  hipFuncSetAttribute((const void*)gemm8p<0>,
                      hipFuncAttributeMaxDynamicSharedMemorySize, 131072);

  hipLaunchKernelGGL(nrm_kernel, dim3(NM), dim3(256), 0, stream, mem, memn);
  hipLaunchKernelGGL(nrm_kernel, dim3(NB), dim3(256), 0, stream, q, qn);
  hipLaunchKernelGGL(tr_kernel, dim3(ND / 64, NM / 64), dim3(256), 0, stream, memn, memt);

  // E = exp(qn * memn^T) bf16 + psum : M=4096, N=8192, K=1024; 512 tiles.
  hipLaunchKernelGGL((gemm8p<1>), dim3((NB / 256) * (NM / 256)), dim3(512), 131072, stream,
                     qn, memn, (void*)E, psum, ND, NM, NB / 256,
                     (NB / 256) * (NM / 256), ND, 0ULL);

  // attn = E / s (fp32 out) + sinv
  hipLaunchKernelGGL(scale_kernel, dim3(NB), dim3(256), 0, stream, E, psum, attn, sinv);

  // part[k] = E * memt^T (k-slice) : M=4096, N=1024, K=8192, S=4 (kchunk 2048)
  const int tps = (NB / 256) * (ND / 256);   // 64
  hipLaunchKernelGGL((gemm8p<0>), dim3(tps * 4), dim3(512), 131072, stream,
                     E, memt, (void*)part, (float*)nullptr, NM, ND, NB / 256, tps, NM / 4,
                     (unsigned long long)NB * ND);
  hipLaunchKernelGGL(reduce_kernel, dim3(2048), dim3(256), 0, stream,
                     (const float4*)part, (float4*)mf, sinv);
}